// Round 1
// baseline (136.123 us; speedup 1.0000x reference)
//
#include <hip/hip_runtime.h>
#include <hip/hip_bf16.h>
#include <type_traits>

typedef __bf16 bf16x2_t __attribute__((ext_vector_type(2)));
typedef __bf16 bf16x4_t __attribute__((ext_vector_type(4)));
typedef __bf16 bf16x8_t __attribute__((ext_vector_type(8)));
typedef float f32x4 __attribute__((ext_vector_type(4)));

#define BATCH   8
#define LENGTH  4096
#define NSTATE  256      // K*blk = 128*2
#define KHALF   128      // complex states per batch
#define MTOT    (BATCH*LENGTH)   // 32768 GEMM rows
#define NCHUNK  128
#define LC      32       // LENGTH / NCHUNK

// ---------------- transpose B, C to bf16 (tiny: 2 x 256x256) ----------------
__global__ __launch_bounds__(256) void transpose_bc(
    const float* __restrict__ Bsrc, const float* __restrict__ Csrc,
    __bf16* __restrict__ BT, __bf16* __restrict__ CT) {
  const float* src = blockIdx.y ? Csrc : Bsrc;
  __bf16* dst      = blockIdx.y ? CT   : BT;
  int n  = blockIdx.x;      // output row (N dim)
  int kk = threadIdx.x;     // output col (K dim)
  dst[n * 256 + kk] = (__bf16)src[kk * 256 + n];
}

// ---------------- GEMM: D[M,256] = A[M,256] * BT[256,256]^T ----------------
// A row-major (M x K), BT row-major (N x K) i.e. B transposed.
// 128x128 block tile, BK=32, 4 waves each computing 64x64 via 4x4 of 16x16x32 MFMA.
template <typename AT, typename OT>
__global__ __launch_bounds__(256) void gemm_bt(const AT* __restrict__ Ag,
                                               const __bf16* __restrict__ BTg,
                                               OT* __restrict__ Dg) {
  __shared__ __align__(16) __bf16 sA[128][32];
  __shared__ __align__(16) __bf16 sB[128][32];

  const int tid  = threadIdx.x;
  const int lane = tid & 63;
  const int wave = tid >> 6;
  const int wr   = wave >> 1;       // wave row (0..1)
  const int wc   = wave & 1;        // wave col (0..1)
  const int m_l  = lane & 15;
  const int quad = lane >> 4;
  const int m0   = blockIdx.x * 128;
  const int n0   = blockIdx.y * 128;

  f32x4 acc[4][4];
#pragma unroll
  for (int mi = 0; mi < 4; ++mi)
#pragma unroll
    for (int ni = 0; ni < 4; ++ni)
#pragma unroll
      for (int r = 0; r < 4; ++r) acc[mi][ni][r] = 0.f;

  for (int kc = 0; kc < 256; kc += 32) {
    if constexpr (std::is_same<AT, float>::value) {
      // fp32 A: load float4, convert to bf16 in-register, stage to LDS
#pragma unroll
      for (int i = 0; i < 4; ++i) {
        int s   = tid + i * 256;          // 0..1023 segments of 4 floats
        int row = s >> 3;
        int c4  = (s & 7) * 4;
        const float4 v = *(const float4*)(Ag + (size_t)(m0 + row) * 256 + kc + c4);
        bf16x4_t b4;
        b4[0] = (__bf16)v.x; b4[1] = (__bf16)v.y;
        b4[2] = (__bf16)v.z; b4[3] = (__bf16)v.w;
        *(bf16x4_t*)&sA[row][c4] = b4;
      }
    } else {
      // bf16 A: 16B vector copies
#pragma unroll
      for (int i = 0; i < 2; ++i) {
        int s   = tid + i * 256;          // 0..511 segments of 8 bf16
        int row = s >> 2;
        int c8  = (s & 3) * 8;
        *(int4*)&sA[row][c8] = *(const int4*)(Ag + (size_t)(m0 + row) * 256 + kc + c8);
      }
    }
#pragma unroll
    for (int i = 0; i < 2; ++i) {
      int s   = tid + i * 256;
      int row = s >> 2;
      int c8  = (s & 3) * 8;
      *(int4*)&sB[row][c8] = *(const int4*)(BTg + (size_t)(n0 + row) * 256 + kc + c8);
    }
    __syncthreads();

    bf16x8_t af[4], bfr[4];
#pragma unroll
    for (int mi = 0; mi < 4; ++mi)
      af[mi] = *(const bf16x8_t*)&sA[wr * 64 + mi * 16 + m_l][quad * 8];
#pragma unroll
    for (int ni = 0; ni < 4; ++ni)
      bfr[ni] = *(const bf16x8_t*)&sB[wc * 64 + ni * 16 + m_l][quad * 8];
#pragma unroll
    for (int mi = 0; mi < 4; ++mi)
#pragma unroll
      for (int ni = 0; ni < 4; ++ni)
        acc[mi][ni] = __builtin_amdgcn_mfma_f32_16x16x32_bf16(af[mi], bfr[ni], acc[mi][ni], 0, 0, 0);
    __syncthreads();
  }

  // epilogue: C/D layout col = lane&15, row = quad*4 + r
#pragma unroll
  for (int mi = 0; mi < 4; ++mi)
#pragma unroll
    for (int ni = 0; ni < 4; ++ni)
#pragma unroll
      for (int r = 0; r < 4; ++r) {
        int row = m0 + wr * 64 + mi * 16 + quad * 4 + r;
        int col = n0 + wc * 64 + ni * 16 + m_l;
        if constexpr (std::is_same<OT, float>::value)
          Dg[(size_t)row * 256 + col] = acc[mi][ni][r];
        else
          Dg[(size_t)row * 256 + col] = (__bf16)acc[mi][ni][r];
      }
}

// ---------------- scan phase 1: per-chunk local partial (zero init) ----------------
// block = (chunk, b), 128 threads = one complex state each. Row reads are 512B coalesced.
__global__ __launch_bounds__(128) void scan_partial(const __bf16* __restrict__ uB,
                                                    const float* __restrict__ Aarr,
                                                    float2* __restrict__ P) {
  const int k     = threadIdx.x;
  const int chunk = blockIdx.x;
  const int b     = blockIdx.y;
  const float c = Aarr[4 * k], s = Aarr[4 * k + 1];
  float hr = 0.f, hi = 0.f;
  const __bf16* p = uB + ((size_t)(b * LENGTH + chunk * LC)) * 256 + 2 * k;
#pragma unroll 8
  for (int j = 0; j < LC; ++j) {
    bf16x2_t u2 = *(const bf16x2_t*)p;
    p += 256;
    float t = fmaf(hr, c, fmaf(-hi, s, (float)u2[0]));
    hi      = fmaf(hr, s, fmaf( hi, c, (float)u2[1]));
    hr = t;
  }
  P[((size_t)b * NCHUNK + chunk) * KHALF + k] = make_float2(hr, hi);
}

// ---------------- scan phase 2: sequential carry combine across chunks ----------------
__global__ __launch_bounds__(128) void scan_carry(const float* __restrict__ Aarr,
                                                  const float* __restrict__ x0,
                                                  const float2* __restrict__ P,
                                                  float2* __restrict__ H,
                                                  float* __restrict__ state_out) {
  const int k = threadIdx.x;
  const int b = blockIdx.x;
  const float c = Aarr[4 * k], s = Aarr[4 * k + 1];
  // w^LC via 5 squarings (LC = 32), |w| = 1 so no drift blowup
  float wr = c, wi = s;
#pragma unroll
  for (int i = 0; i < 5; ++i) {
    float nr = wr * wr - wi * wi;
    float ni = 2.f * wr * wi;
    wr = nr; wi = ni;
  }
  float hr = x0[b * 256 + 2 * k], hi = x0[b * 256 + 2 * k + 1];
#pragma unroll 4
  for (int ch = 0; ch < NCHUNK; ++ch) {
    H[((size_t)b * NCHUNK + ch) * KHALF + k] = make_float2(hr, hi);
    float2 pv = P[((size_t)b * NCHUNK + ch) * KHALF + k];
    float t = fmaf(hr, wr, fmaf(-hi, wi, pv.x));
    hi      = fmaf(hr, wi, fmaf( hi, wr, pv.y));
    hr = t;
  }
  state_out[b * 256 + 2 * k]     = hr;  // new_state (fp32, exact carry chain)
  state_out[b * 256 + 2 * k + 1] = hi;
}

// ---------------- scan phase 3: replay local scan with carry-in, emit x (bf16) ----------------
__global__ __launch_bounds__(128) void scan_apply(const __bf16* __restrict__ uB,
                                                  const float* __restrict__ Aarr,
                                                  const float2* __restrict__ H,
                                                  __bf16* __restrict__ X) {
  const int k     = threadIdx.x;
  const int chunk = blockIdx.x;
  const int b     = blockIdx.y;
  const float c = Aarr[4 * k], s = Aarr[4 * k + 1];
  float2 h = H[((size_t)b * NCHUNK + chunk) * KHALF + k];
  float hr = h.x, hi = h.y;
  const __bf16* pin = uB + ((size_t)(b * LENGTH + chunk * LC)) * 256 + 2 * k;
  __bf16*       po  = (__bf16*)X + ((size_t)(b * LENGTH + chunk * LC)) * 256 + 2 * k;
#pragma unroll 8
  for (int j = 0; j < LC; ++j) {
    bf16x2_t u2 = *(const bf16x2_t*)pin;
    pin += 256;
    float t = fmaf(hr, c, fmaf(-hi, s, (float)u2[0]));
    hi      = fmaf(hr, s, fmaf( hi, c, (float)u2[1]));
    hr = t;
    bf16x2_t o;
    o[0] = (__bf16)hr; o[1] = (__bf16)hi;
    *(bf16x2_t*)po = o;
    po += 256;
  }
}

extern "C" void kernel_launch(void* const* d_in, const int* in_sizes, int n_in,
                              void* d_out, int out_size, void* d_ws, size_t ws_size,
                              hipStream_t stream) {
  const float* u  = (const float*)d_in[0];   // (8, 4096, 256)
  const float* x0 = (const float*)d_in[1];   // (8, 128, 2)
  const float* A  = (const float*)d_in[2];   // (128, 2, 2)
  const float* B  = (const float*)d_in[3];   // (256, 256)
  const float* C  = (const float*)d_in[4];   // (256, 256)

  float* y         = (float*)d_out;                       // (8, 4096, 256)
  float* state_out = y + (size_t)MTOT * 256;              // (8, 128, 2)

  char* ws = (char*)d_ws;
  __bf16* BT = (__bf16*)ws;  ws += 256 * 256 * 2;
  __bf16* CT = (__bf16*)ws;  ws += 256 * 256 * 2;
  __bf16* uB = (__bf16*)ws;  ws += (size_t)MTOT * 256 * 2;
  __bf16* X  = (__bf16*)ws;  ws += (size_t)MTOT * 256 * 2;
  float2* P  = (float2*)ws;  ws += (size_t)BATCH * NCHUNK * KHALF * sizeof(float2);
  float2* H  = (float2*)ws;  ws += (size_t)BATCH * NCHUNK * KHALF * sizeof(float2);

  transpose_bc<<<dim3(256, 2), 256, 0, stream>>>(B, C, BT, CT);
  gemm_bt<float, __bf16><<<dim3(MTOT / 128, 2), 256, 0, stream>>>(u, BT, uB);
  scan_partial<<<dim3(NCHUNK, BATCH), 128, 0, stream>>>(uB, A, P);
  scan_carry<<<dim3(BATCH), 128, 0, stream>>>(A, x0, P, H, state_out);
  scan_apply<<<dim3(NCHUNK, BATCH), 128, 0, stream>>>(uB, A, H, X);
  gemm_bt<__bf16, float><<<dim3(MTOT / 128, 2), 256, 0, stream>>>(X, CT, y);
}

// Round 2
// 121.776 us; speedup vs baseline: 1.1178x; 1.1178x over previous
//
#include <hip/hip_runtime.h>
#include <hip/hip_bf16.h>

typedef __bf16 bf16x2_t __attribute__((ext_vector_type(2)));
typedef __bf16 bf16x8_t __attribute__((ext_vector_type(8)));
typedef float f32x4 __attribute__((ext_vector_type(4)));

#define BATCH   8
#define LENGTH  4096
#define KHALF   128
#define MTOT    (BATCH*LENGTH)
#define NCHUNK  128
#define LC      32

// 16B-chunk XOR swizzle: chunk index ^ (row & 7). Keeps b128 frag reads and
// bf16x2 scan accesses at <=2-way bank conflict with ZERO padding (64KB fits).
#define SWZ(ch, row) ((ch) ^ ((row) & 7))

// ---------------- transpose B, C to bf16 ----------------
__global__ __launch_bounds__(256) void transpose_bc(
    const float* __restrict__ Bsrc, const float* __restrict__ Csrc,
    __bf16* __restrict__ BT, __bf16* __restrict__ CT) {
  const float* src = blockIdx.y ? Csrc : Bsrc;
  __bf16* dst      = blockIdx.y ? CT   : BT;
  int n  = blockIdx.x;
  int kk = threadIdx.x;
  dst[n * 256 + kk] = (__bf16)src[kk * 256 + n];
}

// ---------------- GEMM1: uB = u @ B, fused chunk-partial scan ----------------
// Stage whole 128x256 fp32 A-panel -> bf16 swizzled LDS once; B-frags from L2;
// barrier-free K-loop; epilogue writes uB + computes P for this block's 4 chunks.
__global__ __launch_bounds__(256) void gemm1_fused(
    const float* __restrict__ u, const __bf16* __restrict__ BT,
    const float* __restrict__ Aarr,
    __bf16* __restrict__ uB, float2* __restrict__ P) {
  __shared__ __align__(16) __bf16 sA[128 * 256];   // 64 KB

  const int tid  = threadIdx.x;
  const int lane = tid & 63;
  const int wave = tid >> 6;
  const int wr   = wave >> 1, wc = wave & 1;
  const int m_l  = lane & 15, quad = lane >> 4;
  const int m0   = blockIdx.x * 128;
  const int n0   = blockIdx.y * 128;
  const int b    = m0 >> 12;
  const int t0   = m0 & 4095;

  // stage u (fp32 -> bf16), swizzled 16B chunks, coalesced-pair loads
#pragma unroll
  for (int i = 0; i < 16; ++i) {
    int s   = tid + i * 256;          // 0..4095 chunks of 8 cols
    int row = s >> 5, ch = s & 31;
    const float4* g = (const float4*)(u + (size_t)(m0 + row) * 256 + ch * 8);
    float4 a = g[0], c = g[1];
    bf16x8_t v;
    v[0]=(__bf16)a.x; v[1]=(__bf16)a.y; v[2]=(__bf16)a.z; v[3]=(__bf16)a.w;
    v[4]=(__bf16)c.x; v[5]=(__bf16)c.y; v[6]=(__bf16)c.z; v[7]=(__bf16)c.w;
    *(bf16x8_t*)&sA[row * 256 + SWZ(ch, row) * 8] = v;
  }
  __syncthreads();

  f32x4 acc[4][4];
#pragma unroll
  for (int mi = 0; mi < 4; ++mi)
#pragma unroll
    for (int ni = 0; ni < 4; ++ni)
#pragma unroll
      for (int r = 0; r < 4; ++r) acc[mi][ni][r] = 0.f;

#pragma unroll
  for (int kc8 = 0; kc8 < 8; ++kc8) {     // kc = kc8*32, NO barriers
    bf16x8_t af[4], bfr[4];
#pragma unroll
    for (int mi = 0; mi < 4; ++mi) {
      int row = wr * 64 + mi * 16 + m_l;
      int c   = kc8 * 4 + quad;
      af[mi] = *(const bf16x8_t*)&sA[row * 256 + SWZ(c, row) * 8];
    }
#pragma unroll
    for (int ni = 0; ni < 4; ++ni) {
      int n = n0 + wc * 64 + ni * 16 + m_l;
      bfr[ni] = *(const bf16x8_t*)(BT + (size_t)n * 256 + kc8 * 32 + quad * 8);
    }
#pragma unroll
    for (int mi = 0; mi < 4; ++mi)
#pragma unroll
      for (int ni = 0; ni < 4; ++ni)
        acc[mi][ni] = __builtin_amdgcn_mfma_f32_16x16x32_bf16(af[mi], bfr[ni], acc[mi][ni], 0, 0, 0);
  }
  __syncthreads();   // all waves done reading sA before reuse

  // epilogue: write uB global + bf16 acc tile into LDS (reuse sA, [128][128] swizzled)
  __bf16* sT = sA;
#pragma unroll
  for (int mi = 0; mi < 4; ++mi)
#pragma unroll
    for (int ni = 0; ni < 4; ++ni)
#pragma unroll
      for (int r = 0; r < 4; ++r) {
        int row = wr * 64 + mi * 16 + quad * 4 + r;
        int col = wc * 64 + ni * 16 + m_l;
        __bf16 val = (__bf16)acc[mi][ni][r];
        uB[(size_t)(m0 + row) * 256 + n0 + col] = val;
        sT[row * 128 + SWZ(col >> 3, row) * 8 + (col & 7)] = val;
      }
  __syncthreads();

  // fused scan_partial: 4 chunks x 64 complex states = 256 scans, one per thread
  {
    int kl  = tid & 63;
    int chl = tid >> 6;
    int kg  = (n0 >> 1) + kl;
    float cc = Aarr[4 * kg], sv = Aarr[4 * kg + 1];
    float hr = 0.f, hi = 0.f;
#pragma unroll 8
    for (int j = 0; j < LC; ++j) {
      int row = chl * 32 + j;
      int col = 2 * kl;
      bf16x2_t v2 = *(const bf16x2_t*)&sT[row * 128 + SWZ(col >> 3, row) * 8 + (col & 7)];
      float t = fmaf(hr, cc, fmaf(-hi, sv, (float)v2[0]));
      hi      = fmaf(hr, sv, fmaf( hi, cc, (float)v2[1]));
      hr = t;
    }
    int chg = (t0 >> 5) + chl;
    P[((size_t)b * NCHUNK + chg) * KHALF + kg] = make_float2(hr, hi);
  }
}

// ---------------- wave-parallel carry: one wave per (b,k), Kogge-Stone ----------------
__global__ __launch_bounds__(256) void scan_carry2(
    const float* __restrict__ Aarr, const float* __restrict__ x0,
    const float2* __restrict__ P, float2* __restrict__ H,
    float* __restrict__ state_out) {
  const int lane = threadIdx.x & 63;
  const int wv   = threadIdx.x >> 6;
  const int p    = blockIdx.x * 4 + wv;   // 0..1023 (b,k) pairs
  const int b    = p >> 7, k = p & 127;
  const float cc = Aarr[4 * k], sv = Aarr[4 * k + 1];

  // w32 = w^32 via 5 squarings
  float wr = cc, wi = sv;
#pragma unroll
  for (int i = 0; i < 5; ++i) { float nr = wr*wr - wi*wi; wi = 2.f*wr*wi; wr = nr; }
  // W[s] = w64^(2^s), s=0..5
  float Wr[6], Wi[6];
  Wr[0] = wr*wr - wi*wi; Wi[0] = 2.f*wr*wi;
#pragma unroll
  for (int s = 1; s < 6; ++s) { Wr[s] = Wr[s-1]*Wr[s-1] - Wi[s-1]*Wi[s-1]; Wi[s] = 2.f*Wr[s-1]*Wi[s-1]; }

  float2 P0 = P[((size_t)b * NCHUNK + 2 * lane)     * KHALF + k];
  float2 P1 = P[((size_t)b * NCHUNK + 2 * lane + 1) * KHALF + k];
  // pair combine: q = w32*P0 + P1  (segment scale w64)
  float qr = fmaf(wr, P0.x, fmaf(-wi, P0.y, P1.x));
  float qi = fmaf(wr, P0.y, fmaf( wi, P0.x, P1.y));
  // inclusive scan over lanes: S_L = sum_{j<=L} w64^(L-j) q_j
  float Sr = qr, Si = qi;
#pragma unroll
  for (int s = 0; s < 6; ++s) {
    float tr = __shfl_up(Sr, 1 << s, 64);
    float ti = __shfl_up(Si, 1 << s, 64);
    if (lane >= (1 << s)) {
      float nSr = fmaf(Wr[s], tr, fmaf(-Wi[s], ti, Sr));
      float nSi = fmaf(Wr[s], ti, fmaf( Wi[s], tr, Si));
      Sr = nSr; Si = nSi;
    }
  }
  float Ar = __shfl_up(Sr, 1, 64), Ai = __shfl_up(Si, 1, 64);
  if (lane == 0) { Ar = 0.f; Ai = 0.f; }
  // pL = w64^lane
  float pr = 1.f, pi = 0.f;
#pragma unroll
  for (int s = 0; s < 6; ++s)
    if ((lane >> s) & 1) { float nr = pr*Wr[s] - pi*Wi[s]; pi = pr*Wi[s] + pi*Wr[s]; pr = nr; }

  float x0r = x0[b * 256 + 2 * k], x0i = x0[b * 256 + 2 * k + 1];
  float H0r = fmaf(pr, x0r, fmaf(-pi, x0i, Ar));
  float H0i = fmaf(pr, x0i, fmaf( pi, x0r, Ai));
  H[((size_t)b * NCHUNK + 2 * lane) * KHALF + k] = make_float2(H0r, H0i);
  float H1r = fmaf(wr, H0r, fmaf(-wi, H0i, P0.x));
  float H1i = fmaf(wr, H0i, fmaf( wi, H0r, P0.y));
  H[((size_t)b * NCHUNK + 2 * lane + 1) * KHALF + k] = make_float2(H1r, H1i);
  if (lane == 63) {
    state_out[b * 256 + 2 * k]     = fmaf(wr, H1r, fmaf(-wi, H1i, P1.x));
    state_out[b * 256 + 2 * k + 1] = fmaf(wr, H1i, fmaf( wi, H1r, P1.y));
  }
}

// ---------------- GEMM2: y = X @ C, X replayed in-LDS from uB + H ----------------
__global__ __launch_bounds__(256) void gemm2_fused(
    const __bf16* __restrict__ uB, const float* __restrict__ Aarr,
    const float2* __restrict__ H, const __bf16* __restrict__ CT,
    float* __restrict__ Y) {
  __shared__ __align__(16) __bf16 sX[128 * 256];   // 64 KB

  const int tid  = threadIdx.x;
  const int lane = tid & 63;
  const int wave = tid >> 6;
  const int wr   = wave >> 1, wc = wave & 1;
  const int m_l  = lane & 15, quad = lane >> 4;
  const int m0   = blockIdx.x * 128;
  const int n0   = blockIdx.y * 128;
  const int b    = m0 >> 12;
  const int t0   = m0 & 4095;

  // stage uB -> sX (swizzled), perfectly coalesced
#pragma unroll
  for (int i = 0; i < 16; ++i) {
    int s   = tid + i * 256;
    int row = s >> 5, ch = s & 31;
    *(bf16x8_t*)&sX[row * 256 + SWZ(ch, row) * 8] =
        *(const bf16x8_t*)(uB + (size_t)(m0 + row) * 256 + ch * 8);
  }
  __syncthreads();

  // in-LDS scan replay: 4 chunks x 128 k = 512 scans, 2 per thread
  {
    int k   = tid & 127;
    int ch0 = tid >> 7;
    float cc = Aarr[4 * k], sv = Aarr[4 * k + 1];
#pragma unroll
    for (int pass = 0; pass < 2; ++pass) {
      int chl = ch0 + 2 * pass;
      float2 h = H[((size_t)b * NCHUNK + (t0 >> 5) + chl) * KHALF + k];
      float hr = h.x, hi = h.y;
#pragma unroll 8
      for (int j = 0; j < LC; ++j) {
        int row = chl * 32 + j;
        int idx = row * 256 + SWZ(k >> 2, row) * 8 + ((2 * k) & 7);
        bf16x2_t v2 = *(const bf16x2_t*)&sX[idx];
        float t = fmaf(hr, cc, fmaf(-hi, sv, (float)v2[0]));
        hi      = fmaf(hr, sv, fmaf( hi, cc, (float)v2[1]));
        hr = t;
        bf16x2_t o; o[0] = (__bf16)hr; o[1] = (__bf16)hi;
        *(bf16x2_t*)&sX[idx] = o;
      }
    }
  }
  __syncthreads();

  f32x4 acc[4][4];
#pragma unroll
  for (int mi = 0; mi < 4; ++mi)
#pragma unroll
    for (int ni = 0; ni < 4; ++ni)
#pragma unroll
      for (int r = 0; r < 4; ++r) acc[mi][ni][r] = 0.f;

#pragma unroll
  for (int kc8 = 0; kc8 < 8; ++kc8) {     // barrier-free K-loop
    bf16x8_t af[4], bfr[4];
#pragma unroll
    for (int mi = 0; mi < 4; ++mi) {
      int row = wr * 64 + mi * 16 + m_l;
      int c   = kc8 * 4 + quad;
      af[mi] = *(const bf16x8_t*)&sX[row * 256 + SWZ(c, row) * 8];
    }
#pragma unroll
    for (int ni = 0; ni < 4; ++ni) {
      int n = n0 + wc * 64 + ni * 16 + m_l;
      bfr[ni] = *(const bf16x8_t*)(CT + (size_t)n * 256 + kc8 * 32 + quad * 8);
    }
#pragma unroll
    for (int mi = 0; mi < 4; ++mi)
#pragma unroll
      for (int ni = 0; ni < 4; ++ni)
        acc[mi][ni] = __builtin_amdgcn_mfma_f32_16x16x32_bf16(af[mi], bfr[ni], acc[mi][ni], 0, 0, 0);
  }

#pragma unroll
  for (int mi = 0; mi < 4; ++mi)
#pragma unroll
    for (int ni = 0; ni < 4; ++ni)
#pragma unroll
      for (int r = 0; r < 4; ++r) {
        int row = m0 + wr * 64 + mi * 16 + quad * 4 + r;
        int col = n0 + wc * 64 + ni * 16 + m_l;
        Y[(size_t)row * 256 + col] = acc[mi][ni][r];
      }
}

extern "C" void kernel_launch(void* const* d_in, const int* in_sizes, int n_in,
                              void* d_out, int out_size, void* d_ws, size_t ws_size,
                              hipStream_t stream) {
  const float* u  = (const float*)d_in[0];
  const float* x0 = (const float*)d_in[1];
  const float* A  = (const float*)d_in[2];
  const float* B  = (const float*)d_in[3];
  const float* C  = (const float*)d_in[4];

  float* y         = (float*)d_out;
  float* state_out = y + (size_t)MTOT * 256;

  char* ws = (char*)d_ws;
  __bf16* BT = (__bf16*)ws;  ws += 256 * 256 * 2;
  __bf16* CT = (__bf16*)ws;  ws += 256 * 256 * 2;
  __bf16* uB = (__bf16*)ws;  ws += (size_t)MTOT * 256 * 2;
  float2* P  = (float2*)ws;  ws += (size_t)BATCH * NCHUNK * KHALF * sizeof(float2);
  float2* H  = (float2*)ws;  ws += (size_t)BATCH * NCHUNK * KHALF * sizeof(float2);

  transpose_bc<<<dim3(256, 2), 256, 0, stream>>>(B, C, BT, CT);
  gemm1_fused<<<dim3(MTOT / 128, 2), 256, 0, stream>>>(u, BT, A, uB, P);
  scan_carry2<<<dim3(256), 256, 0, stream>>>(A, x0, P, H, state_out);
  gemm2_fused<<<dim3(MTOT / 128, 2), 256, 0, stream>>>(uB, A, H, CT, y);
}

// Round 3
// 119.361 us; speedup vs baseline: 1.1404x; 1.0202x over previous
//
#include <hip/hip_runtime.h>
#include <hip/hip_bf16.h>

typedef __bf16 bf16x2_t __attribute__((ext_vector_type(2)));
typedef __bf16 bf16x8_t __attribute__((ext_vector_type(8)));
typedef float f32x4 __attribute__((ext_vector_type(4)));

#define BATCH   8
#define LENGTH  4096
#define KHALF   128
#define MTOT    (BATCH*LENGTH)
#define NCHUNK  128
#define LC      32

// 16B-chunk XOR swizzle: chunk index ^ (row & 7). Keeps b128 frag reads and
// bf16x2 scan accesses at <=2-way bank conflict with ZERO padding.
#define SWZ(ch, row) ((ch) ^ ((row) & 7))

// ---------------- transpose B, C to bf16 ----------------
__global__ __launch_bounds__(256) void transpose_bc(
    const float* __restrict__ Bsrc, const float* __restrict__ Csrc,
    __bf16* __restrict__ BT, __bf16* __restrict__ CT) {
  const float* src = blockIdx.y ? Csrc : Bsrc;
  __bf16* dst      = blockIdx.y ? CT   : BT;
  int n  = blockIdx.x;
  int kk = threadIdx.x;
  dst[n * 256 + kk] = (__bf16)src[kk * 256 + n];
}

// ---------------- GEMM1: uB = u @ B (64x256 tile, full N), fused chunk-partial scan ----
// Stage 64x256 fp32 u-panel -> bf16 swizzled LDS ONCE (u read exactly once);
// B-frags from L2; barrier-free K-loop; epilogue stashes bf16 tile in LDS,
// does coalesced uB write + per-chunk partial scan (P).
__global__ __launch_bounds__(256) void gemm1_fused(
    const float* __restrict__ u, const __bf16* __restrict__ BT,
    const float* __restrict__ Aarr,
    __bf16* __restrict__ uB, float2* __restrict__ P) {
  __shared__ __align__(16) __bf16 sA[64 * 256];   // 32 KB

  const int tid  = threadIdx.x;
  const int lane = tid & 63;
  const int wave = tid >> 6;          // wave = column group (0..3)
  const int m_l  = lane & 15, quad = lane >> 4;
  const int m0   = blockIdx.x * 64;
  const int b    = m0 >> 12;
  const int t0   = m0 & 4095;

  // stage u (fp32 -> bf16), swizzled 16B chunks
#pragma unroll
  for (int i = 0; i < 8; ++i) {
    int s   = tid + i * 256;          // 0..2047 chunks of 8 cols
    int row = s >> 5, ch = s & 31;
    const float4* g = (const float4*)(u + (size_t)(m0 + row) * 256 + ch * 8);
    float4 a = g[0], c = g[1];
    bf16x8_t v;
    v[0]=(__bf16)a.x; v[1]=(__bf16)a.y; v[2]=(__bf16)a.z; v[3]=(__bf16)a.w;
    v[4]=(__bf16)c.x; v[5]=(__bf16)c.y; v[6]=(__bf16)c.z; v[7]=(__bf16)c.w;
    *(bf16x8_t*)&sA[row * 256 + SWZ(ch, row) * 8] = v;
  }
  __syncthreads();

  f32x4 acc[4][4];
#pragma unroll
  for (int mi = 0; mi < 4; ++mi)
#pragma unroll
    for (int ni = 0; ni < 4; ++ni)
#pragma unroll
      for (int r = 0; r < 4; ++r) acc[mi][ni][r] = 0.f;

#pragma unroll
  for (int kc8 = 0; kc8 < 8; ++kc8) {     // NO barriers in K-loop
    bf16x8_t af[4], bfr[4];
#pragma unroll
    for (int mi = 0; mi < 4; ++mi) {
      int row = mi * 16 + m_l;
      int c   = kc8 * 4 + quad;
      af[mi] = *(const bf16x8_t*)&sA[row * 256 + SWZ(c, row) * 8];
    }
#pragma unroll
    for (int ni = 0; ni < 4; ++ni) {
      int n = wave * 64 + ni * 16 + m_l;
      bfr[ni] = *(const bf16x8_t*)(BT + (size_t)n * 256 + kc8 * 32 + quad * 8);
    }
#pragma unroll
    for (int mi = 0; mi < 4; ++mi)
#pragma unroll
      for (int ni = 0; ni < 4; ++ni)
        acc[mi][ni] = __builtin_amdgcn_mfma_f32_16x16x32_bf16(af[mi], bfr[ni], acc[mi][ni], 0, 0, 0);
  }
  __syncthreads();   // done reading sA; reuse as output stash

  // stash bf16 64x256 tile into LDS (swizzled)
  __bf16* sT = sA;
#pragma unroll
  for (int mi = 0; mi < 4; ++mi)
#pragma unroll
    for (int ni = 0; ni < 4; ++ni)
#pragma unroll
      for (int r = 0; r < 4; ++r) {
        int row = mi * 16 + quad * 4 + r;
        int col = wave * 64 + ni * 16 + m_l;
        sT[row * 256 + SWZ(col >> 3, row) * 8 + (col & 7)] = (__bf16)acc[mi][ni][r];
      }
  __syncthreads();

  // coalesced uB write from LDS
#pragma unroll
  for (int i = 0; i < 8; ++i) {
    int s   = tid + i * 256;
    int row = s >> 5, ch = s & 31;
    *(bf16x8_t*)(uB + (size_t)(m0 + row) * 256 + ch * 8) =
        *(const bf16x8_t*)&sT[row * 256 + SWZ(ch, row) * 8];
  }

  // fused scan_partial: 2 chunks x 128 complex states = 256 scans, one per thread
  {
    int k   = tid & 127;
    int chl = tid >> 7;               // 0..1
    float cc = Aarr[4 * k], sv = Aarr[4 * k + 1];
    float hr = 0.f, hi = 0.f;
#pragma unroll 8
    for (int j = 0; j < LC; ++j) {
      int row = chl * 32 + j;
      bf16x2_t v2 = *(const bf16x2_t*)&sT[row * 256 + SWZ(k >> 2, row) * 8 + ((2 * k) & 7)];
      float t = fmaf(hr, cc, fmaf(-hi, sv, (float)v2[0]));
      hi      = fmaf(hr, sv, fmaf( hi, cc, (float)v2[1]));
      hr = t;
    }
    int chg = (t0 >> 5) + chl;
    P[((size_t)b * NCHUNK + chg) * KHALF + k] = make_float2(hr, hi);
  }
}

// ---------------- wave-parallel carry: one wave per (b,k), Kogge-Stone ----------------
__global__ __launch_bounds__(256) void scan_carry2(
    const float* __restrict__ Aarr, const float* __restrict__ x0,
    const float2* __restrict__ P, float2* __restrict__ H,
    float* __restrict__ state_out) {
  const int lane = threadIdx.x & 63;
  const int wv   = threadIdx.x >> 6;
  const int p    = blockIdx.x * 4 + wv;   // 0..1023 (b,k) pairs
  const int b    = p >> 7, k = p & 127;
  const float cc = Aarr[4 * k], sv = Aarr[4 * k + 1];

  // w32 = w^32 via 5 squarings
  float wr = cc, wi = sv;
#pragma unroll
  for (int i = 0; i < 5; ++i) { float nr = wr*wr - wi*wi; wi = 2.f*wr*wi; wr = nr; }
  // W[s] = w64^(2^s), s=0..5
  float Wr[6], Wi[6];
  Wr[0] = wr*wr - wi*wi; Wi[0] = 2.f*wr*wi;
#pragma unroll
  for (int s = 1; s < 6; ++s) { Wr[s] = Wr[s-1]*Wr[s-1] - Wi[s-1]*Wi[s-1]; Wi[s] = 2.f*Wr[s-1]*Wi[s-1]; }

  float2 P0 = P[((size_t)b * NCHUNK + 2 * lane)     * KHALF + k];
  float2 P1 = P[((size_t)b * NCHUNK + 2 * lane + 1) * KHALF + k];
  // pair combine: q = w32*P0 + P1  (segment scale w64)
  float qr = fmaf(wr, P0.x, fmaf(-wi, P0.y, P1.x));
  float qi = fmaf(wr, P0.y, fmaf( wi, P0.x, P1.y));
  // inclusive scan over lanes
  float Sr = qr, Si = qi;
#pragma unroll
  for (int s = 0; s < 6; ++s) {
    float tr = __shfl_up(Sr, 1 << s, 64);
    float ti = __shfl_up(Si, 1 << s, 64);
    if (lane >= (1 << s)) {
      float nSr = fmaf(Wr[s], tr, fmaf(-Wi[s], ti, Sr));
      float nSi = fmaf(Wr[s], ti, fmaf( Wi[s], tr, Si));
      Sr = nSr; Si = nSi;
    }
  }
  float Ar = __shfl_up(Sr, 1, 64), Ai = __shfl_up(Si, 1, 64);
  if (lane == 0) { Ar = 0.f; Ai = 0.f; }
  // pL = w64^lane
  float pr = 1.f, pi = 0.f;
#pragma unroll
  for (int s = 0; s < 6; ++s)
    if ((lane >> s) & 1) { float nr = pr*Wr[s] - pi*Wi[s]; pi = pr*Wi[s] + pi*Wr[s]; pr = nr; }

  float x0r = x0[b * 256 + 2 * k], x0i = x0[b * 256 + 2 * k + 1];
  float H0r = fmaf(pr, x0r, fmaf(-pi, x0i, Ar));
  float H0i = fmaf(pr, x0i, fmaf( pi, x0r, Ai));
  H[((size_t)b * NCHUNK + 2 * lane) * KHALF + k] = make_float2(H0r, H0i);
  float H1r = fmaf(wr, H0r, fmaf(-wi, H0i, P0.x));
  float H1i = fmaf(wr, H0i, fmaf( wi, H0r, P0.y));
  H[((size_t)b * NCHUNK + 2 * lane + 1) * KHALF + k] = make_float2(H1r, H1i);
  if (lane == 63) {
    state_out[b * 256 + 2 * k]     = fmaf(wr, H1r, fmaf(-wi, H1i, P1.x));
    state_out[b * 256 + 2 * k + 1] = fmaf(wr, H1i, fmaf( wi, H1r, P1.y));
  }
}

// ---------------- GEMM2: y = X @ C (64x256 tile, full N), X replayed in-LDS ------------
__global__ __launch_bounds__(256) void gemm2_fused(
    const __bf16* __restrict__ uB, const float* __restrict__ Aarr,
    const float2* __restrict__ H, const __bf16* __restrict__ CT,
    float* __restrict__ Y) {
  __shared__ __align__(16) __bf16 sX[64 * 256];   // 32 KB

  const int tid  = threadIdx.x;
  const int lane = tid & 63;
  const int wave = tid >> 6;
  const int m_l  = lane & 15, quad = lane >> 4;
  const int m0   = blockIdx.x * 64;
  const int b    = m0 >> 12;
  const int t0   = m0 & 4095;

  // stage uB -> sX (swizzled), uB read exactly once
#pragma unroll
  for (int i = 0; i < 8; ++i) {
    int s   = tid + i * 256;
    int row = s >> 5, ch = s & 31;
    *(bf16x8_t*)&sX[row * 256 + SWZ(ch, row) * 8] =
        *(const bf16x8_t*)(uB + (size_t)(m0 + row) * 256 + ch * 8);
  }
  __syncthreads();

  // in-LDS scan replay: 2 chunks x 128 k = 256 scans, one per thread (disjoint RMW)
  {
    int k   = tid & 127;
    int chl = tid >> 7;
    float cc = Aarr[4 * k], sv = Aarr[4 * k + 1];
    float2 h = H[((size_t)b * NCHUNK + (t0 >> 5) + chl) * KHALF + k];
    float hr = h.x, hi = h.y;
#pragma unroll 8
    for (int j = 0; j < LC; ++j) {
      int row = chl * 32 + j;
      int idx = row * 256 + SWZ(k >> 2, row) * 8 + ((2 * k) & 7);
      bf16x2_t v2 = *(const bf16x2_t*)&sX[idx];
      float t = fmaf(hr, cc, fmaf(-hi, sv, (float)v2[0]));
      hi      = fmaf(hr, sv, fmaf( hi, cc, (float)v2[1]));
      hr = t;
      bf16x2_t o; o[0] = (__bf16)hr; o[1] = (__bf16)hi;
      *(bf16x2_t*)&sX[idx] = o;
    }
  }
  __syncthreads();

  f32x4 acc[4][4];
#pragma unroll
  for (int mi = 0; mi < 4; ++mi)
#pragma unroll
    for (int ni = 0; ni < 4; ++ni)
#pragma unroll
      for (int r = 0; r < 4; ++r) acc[mi][ni][r] = 0.f;

#pragma unroll
  for (int kc8 = 0; kc8 < 8; ++kc8) {     // barrier-free K-loop
    bf16x8_t af[4], bfr[4];
#pragma unroll
    for (int mi = 0; mi < 4; ++mi) {
      int row = mi * 16 + m_l;
      int c   = kc8 * 4 + quad;
      af[mi] = *(const bf16x8_t*)&sX[row * 256 + SWZ(c, row) * 8];
    }
#pragma unroll
    for (int ni = 0; ni < 4; ++ni) {
      int n = wave * 64 + ni * 16 + m_l;
      bfr[ni] = *(const bf16x8_t*)(CT + (size_t)n * 256 + kc8 * 32 + quad * 8);
    }
#pragma unroll
    for (int mi = 0; mi < 4; ++mi)
#pragma unroll
      for (int ni = 0; ni < 4; ++ni)
        acc[mi][ni] = __builtin_amdgcn_mfma_f32_16x16x32_bf16(af[mi], bfr[ni], acc[mi][ni], 0, 0, 0);
  }

#pragma unroll
  for (int mi = 0; mi < 4; ++mi)
#pragma unroll
    for (int ni = 0; ni < 4; ++ni)
#pragma unroll
      for (int r = 0; r < 4; ++r) {
        int row = m0 + mi * 16 + quad * 4 + r;
        int col = wave * 64 + ni * 16 + m_l;
        Y[(size_t)row * 256 + col] = acc[mi][ni][r];
      }
}

extern "C" void kernel_launch(void* const* d_in, const int* in_sizes, int n_in,
                              void* d_out, int out_size, void* d_ws, size_t ws_size,
                              hipStream_t stream) {
  const float* u  = (const float*)d_in[0];
  const float* x0 = (const float*)d_in[1];
  const float* A  = (const float*)d_in[2];
  const float* B  = (const float*)d_in[3];
  const float* C  = (const float*)d_in[4];

  float* y         = (float*)d_out;
  float* state_out = y + (size_t)MTOT * 256;

  char* ws = (char*)d_ws;
  __bf16* BT = (__bf16*)ws;  ws += 256 * 256 * 2;
  __bf16* CT = (__bf16*)ws;  ws += 256 * 256 * 2;
  __bf16* uB = (__bf16*)ws;  ws += (size_t)MTOT * 256 * 2;
  float2* P  = (float2*)ws;  ws += (size_t)BATCH * NCHUNK * KHALF * sizeof(float2);
  float2* H  = (float2*)ws;  ws += (size_t)BATCH * NCHUNK * KHALF * sizeof(float2);

  transpose_bc<<<dim3(256, 2), 256, 0, stream>>>(B, C, BT, CT);
  gemm1_fused<<<dim3(MTOT / 64), 256, 0, stream>>>(u, BT, A, uB, P);
  scan_carry2<<<dim3(256), 256, 0, stream>>>(A, x0, P, H, state_out);
  gemm2_fused<<<dim3(MTOT / 64), 256, 0, stream>>>(uB, A, H, CT, y);
}